// Round 14
// baseline (233.033 us; speedup 1.0000x reference)
//
#include <hip/hip_runtime.h>
#include <hip/hip_bf16.h>
#include <stdint.h>

// Problem constants
#define B_   64
#define T_   300
#define NIN  2312
#define H1   512
#define H2   256
#define NOUT 101
#define KP   2368   // NIN padded to multiple of 64
#define NT   (KP / 64)
#define CH   15     // I1 staging chunk (timesteps); 300 = 20*15
#define NC   (T_ / CH)

typedef __attribute__((ext_vector_type(8))) short bf16x8;
typedef __attribute__((ext_vector_type(4))) float f32x4;
typedef __attribute__((ext_vector_type(8))) unsigned short u16x8;

#define LDS_GLOAD16(g, l) \
  __builtin_amdgcn_global_load_lds((const __attribute__((address_space(1))) void*)(g), \
                                   (__attribute__((address_space(3))) void*)(l), 16, 0, 0)

// ---------------- transpose helper ----------------
__global__ void transpose_k(const float* __restrict__ src, float* __restrict__ dst,
                            int R, int C) {
    int idx = blockIdx.x * 256 + threadIdx.x;
    if (idx < R * C) {
        int r = idx / C, c = idx % C;
        dst[c * R + r] = src[r * C + c];
    }
}

// ---------------- fp32 -> bf16 (RNE) with K-padding, float4 loads ----------------
__device__ __forceinline__ unsigned short rne_bf16(float v) {
    union { float f; unsigned u; } cv; cv.f = v;
    return (unsigned short)((cv.u + 0x7fff + ((cv.u >> 16) & 1)) >> 16);
}

__global__ __launch_bounds__(256) void cvt_pad_bf16(const float* __restrict__ src,
                                                    unsigned short* __restrict__ dst,
                                                    int R, int C, int Cp) {
    int idx = blockIdx.x * 256 + threadIdx.x;
    int cpw = Cp >> 3;
    if (idx >= R * cpw) return;
    int row = idx / cpw;
    int c0 = (idx - row * cpw) << 3;
    u16x8 o;
    if (c0 + 8 <= C) {
        const float4* s = (const float4*)(src + (size_t)row * C + c0);
        float4 v0 = s[0], v1 = s[1];
        float v[8] = {v0.x, v0.y, v0.z, v0.w, v1.x, v1.y, v1.z, v1.w};
#pragma unroll
        for (int j = 0; j < 8; ++j) o[j] = rne_bf16(v[j]);
    } else {
#pragma unroll
        for (int j = 0; j < 8; ++j) {
            int k = c0 + j;
            o[j] = (k < C) ? rne_bf16(src[(size_t)row * C + k]) : (unsigned short)0;
        }
    }
    *(u16x8*)(dst + (size_t)row * Cp + c0) = o;
}

// ---- bf16 GEMM, 128(M) x 256(N) tile (unchanged from R13) ----
__global__ __launch_bounds__(512) void gemm_bf16(
    const unsigned short* __restrict__ Xb,   // [M][KP] bf16 bits
    const unsigned short* __restrict__ Wb,   // [H1][KP] bf16 bits
    float* __restrict__ Y)                   // [M][H1]
{
    __shared__ __align__(16) unsigned short As[128][64];   // 16 KB
    __shared__ __align__(16) unsigned short Bs[256][64];   // 32 KB

    const int tid  = threadIdx.x;
    const int wave = tid >> 6, lane = tid & 63;
    const int wr = wave >> 2, wc = wave & 3;          // 2x4 waves, 64x64 each

    // m204 bijective XCD swizzle for 300 blocks (300 % 8 == 4)
    const int d  = blockIdx.x;                        // 0..299
    const int xcd = d & 7, i = d >> 3;
    const int q = 300 / 8, r = 300 % 8;               // 37, 4
    const int wg = (xcd < r) ? xcd * (q + 1) + i : r * (q + 1) + (xcd - r) * q + i;
    const int bn = wg & 1, bm = wg >> 1;
    const int m0 = bm * 128, n0 = bn * 256;
    const int fr = lane & 15, fq = lane >> 4;
    const int swz = (fr & 7) << 3;                    // element XOR for reads

    f32x4 acc[4][4] = {};

    const size_t rowB = (size_t)KP * 2;
    const int colsw = 16 * ((lane & 7) ^ (lane >> 3));          // bytes
    const char* gA = (const char*)Xb + (size_t)(m0 + 16 * wave + (lane >> 3)) * rowB + colsw;
    unsigned short* lA = &As[16 * wave][0];
    const char* gB = (const char*)Wb + (size_t)(n0 + 32 * wave + (lane >> 3)) * rowB + colsw;
    unsigned short* lB = &Bs[32 * wave][0];

    for (int kt = 0; kt < NT; ++kt) {
        const size_t ko = (size_t)kt * 128;           // byte offset along K
#pragma unroll
        for (int s = 0; s < 2; ++s)
            LDS_GLOAD16(gA + ko + (size_t)s * 8 * rowB, lA + s * 8 * 64);
#pragma unroll
        for (int s = 0; s < 4; ++s)
            LDS_GLOAD16(gB + ko + (size_t)s * 8 * rowB, lB + s * 8 * 64);
        __syncthreads();   // compiler drains vmcnt before barrier

#pragma unroll
        for (int ks = 0; ks < 2; ++ks) {
            bf16x8 a[4], b[4];
#pragma unroll
            for (int mi = 0; mi < 4; ++mi)
                a[mi] = *(const bf16x8*)&As[wr * 64 + mi * 16 + fr][(ks * 32 + fq * 8) ^ swz];
#pragma unroll
            for (int nj = 0; nj < 4; ++nj)
                b[nj] = *(const bf16x8*)&Bs[wc * 64 + nj * 16 + fr][(ks * 32 + fq * 8) ^ swz];
#pragma unroll
            for (int mi = 0; mi < 4; ++mi)
#pragma unroll
                for (int nj = 0; nj < 4; ++nj)
                    acc[mi][nj] = __builtin_amdgcn_mfma_f32_16x16x32_bf16(
                        a[mi], b[nj], acc[mi][nj], 0, 0, 0);
        }
        __syncthreads();
    }

    // C/D layout (m89-verified): col = lane&15, row = (lane>>4)*4 + reg
#pragma unroll
    for (int mi = 0; mi < 4; ++mi)
#pragma unroll
        for (int nj = 0; nj < 4; ++nj) {
            int r0 = m0 + wr * 64 + mi * 16 + fq * 4;
            int c  = n0 + wc * 64 + nj * 16 + fr;
#pragma unroll
            for (int rr = 0; rr < 4; ++rr)
                Y[(size_t)(r0 + rr) * H1 + c] = acc[mi][nj][rr];
        }
}

// ---------------- wave-per-batch SNN scan (v7): contiguous ownership ----------
// Lane owns L1 neurons 8*lane+j (j<8) and L2 neurons 4*lane+j (j<4), so each
// spike gather is 2 float4 (wrt) + 1 float4 (w2t) = 3 coalesced instructions
// instead of 12 stride-64 scalars (spikes are NOT rare: steady DC-driven set).
// I1 LDS chunk is stored with an XOR slot swizzle (involution d = g^((g>>3)&7),
// applied on the global SOURCE of global_load_lds) so the per-lane contiguous
// float4-pair read is 2-way-conflict-free (free per m136).
__global__ __launch_bounds__(64) void snn_scan_wave(
    const float* __restrict__ I1ff,   // [B][T][H1]
    const float* __restrict__ wrt,    // [H1][H1]  wrt[i][h] = w_rec[h][i]
    const float* __restrict__ w2t,    // [H1][H2]  w2t[i][g] = w2[g][i]
    const float* __restrict__ w3t,    // [H2][NOUT]
    const float* __restrict__ alpha1, const float* __restrict__ rho1,
    const float* __restrict__ beta_a1,
    const float* __restrict__ alpha2, const float* __restrict__ rho2,
    const float* __restrict__ beta_a2,
    const float* __restrict__ beta_out,
    float* __restrict__ out)          // [B][NOUT]
{
    __shared__ __align__(16) float Ich[2][CH][H1];   // 60 KB

    const int b = blockIdx.x;
    const int lane = threadIdx.x;     // 0..63

    // ---- layer-1 state: neurons h = 8*lane + j ----
    float v1[8], a1[8], s1f[8], al1[8], oml1[8], rh1[8], ba1[8];
    {
        const float4* pa = (const float4*)(alpha1 + 8 * lane);
        const float4* pr = (const float4*)(rho1   + 8 * lane);
        const float4* pb = (const float4*)(beta_a1 + 8 * lane);
        float4 aa = pa[0], ab = pa[1], ra = pr[0], rb = pr[1], ba = pb[0], bb = pb[1];
        float av[8] = {aa.x,aa.y,aa.z,aa.w,ab.x,ab.y,ab.z,ab.w};
        float rv[8] = {ra.x,ra.y,ra.z,ra.w,rb.x,rb.y,rb.z,rb.w};
        float bv[8] = {ba.x,ba.y,ba.z,ba.w,bb.x,bb.y,bb.z,bb.w};
#pragma unroll
        for (int j = 0; j < 8; ++j) {
            v1[j] = 0.f; a1[j] = 0.f; s1f[j] = 0.f;
            al1[j] = av[j]; oml1[j] = 1.f - av[j]; rh1[j] = rv[j]; ba1[j] = bv[j];
        }
    }
    // ---- layer-2 state: neurons h = 4*lane + j ----
    float v2[4], a2[4], s2f[4], al2[4], oml2[4], rh2[4], ba2[4];
    {
        float4 aa = *(const float4*)(alpha2 + 4 * lane);
        float4 ra = *(const float4*)(rho2   + 4 * lane);
        float4 ba = *(const float4*)(beta_a2 + 4 * lane);
        float av[4] = {aa.x,aa.y,aa.z,aa.w};
        float rv[4] = {ra.x,ra.y,ra.z,ra.w};
        float bv[4] = {ba.x,ba.y,ba.z,ba.w};
#pragma unroll
        for (int j = 0; j < 4; ++j) {
            v2[j] = 0.f; a2[j] = 0.f; s2f[j] = 0.f;
            al2[j] = av[j]; oml2[j] = 1.f - av[j]; rh2[j] = rv[j]; ba2[j] = bv[j];
        }
    }
    // ---- readout (o = lane; o = 64+lane if lane < NOUT-64) ----
    float vo0 = 0.f, vo1 = 0.f, vs0 = 0.f, vs1 = 0.f;
    const float bo0 = beta_out[lane];
    const float ombo0 = 1.f - bo0;
    const float bo1 = (lane < NOUT - 64) ? beta_out[64 + lane] : 0.f;
    const float ombo1 = 1.f - bo1;

    unsigned long long M1[8];
#pragma unroll
    for (int j = 0; j < 8; ++j) M1[j] = 0ull;
    bool prev1 = false;

    const float* I1p = I1ff + (size_t)b * T_ * H1;

    // staging with XOR-swizzled SOURCE slot: dest slot d holds global slot
    // g = d ^ ((d>>3)&7); per 64-slot half the lane's source slot is
    // l ^ ((l>>3)&7) (mask indep. of half since 64 ≡ 0 mod 8 slots).
    const int gsl = lane ^ ((lane >> 3) & 7);
    auto stage = [&](int c, int bufi) {
        const float* src = I1p + (size_t)c * CH * H1 + 4 * gsl;
#pragma unroll
        for (int s = 0; s < CH; ++s) {
            LDS_GLOAD16(src + (size_t)s * H1,       &Ich[bufi][s][0]);
            LDS_GLOAD16(src + (size_t)s * H1 + 256, &Ich[bufi][s][256]);
        }
    };

    // read slots for floats [8l..8l+8): d1 = 2l ^ ((l>>2)&7), d2 = d1 ^ 1
    const int rd1 = (2 * lane) ^ ((lane >> 2) & 7);

    stage(0, 0);

    for (int c = 0; c < NC; ++c) {
        const int buf = c & 1;
        asm volatile("s_waitcnt vmcnt(0)" ::: "memory");

        float cur[8];
        {
            const float4* bp = (const float4*)&Ich[buf][0][0];
            float4 c0 = bp[rd1], c1 = bp[rd1 ^ 1];
            cur[0]=c0.x; cur[1]=c0.y; cur[2]=c0.z; cur[3]=c0.w;
            cur[4]=c1.x; cur[5]=c1.y; cur[6]=c1.z; cur[7]=c1.w;
        }

        for (int s = 0; s < CH; ++s) {
            float nxt[8];
            if (s + 1 < CH) {
                const float4* bp = (const float4*)&Ich[buf][s + 1][0];
                float4 c0 = bp[rd1], c1 = bp[rd1 ^ 1];
                nxt[0]=c0.x; nxt[1]=c0.y; nxt[2]=c0.z; nxt[3]=c0.w;
                nxt[4]=c1.x; nxt[5]=c1.y; nxt[6]=c1.z; nxt[7]=c1.w;
            }

            // ---- recurrent input: 2 float4 per spike (coalesced) ----
            float rec[8] = {0.f,0.f,0.f,0.f,0.f,0.f,0.f,0.f};
            if (prev1) {
#pragma unroll
                for (int j = 0; j < 8; ++j) {
                    unsigned long long bits = M1[j];
                    while (bits) {
                        int p = __builtin_ctzll(bits);
                        bits &= bits - 1;
                        int i = (p << 3) + j;               // neuron id
                        const float4* r = (const float4*)(wrt + (size_t)i * H1 + 8 * lane);
                        float4 ra = r[0], rb = r[1];
                        rec[0]+=ra.x; rec[1]+=ra.y; rec[2]+=ra.z; rec[3]+=ra.w;
                        rec[4]+=rb.x; rec[5]+=rb.y; rec[6]+=rb.z; rec[7]+=rb.w;
                    }
                }
            }

            // ---- layer-1 update ----
            unsigned m = 0;
#pragma unroll
            for (int j = 0; j < 8; ++j) {
                float I1v = cur[j] + rec[j];
                float v1n = fmaf(al1[j], v1[j], oml1[j] * (I1v - a1[j]));
                bool  sp  = v1n > 1.f;
                v1[j] = sp ? v1n - 1.f : v1n;
                a1[j] = fmaf(rh1[j], a1[j], ba1[j] * s1f[j]);
                s1f[j] = sp ? 1.f : 0.f;
                m |= (sp ? 1u : 0u) << j;
            }

            unsigned long long anyb = __ballot(m != 0);
            float I2[4] = {0.f, 0.f, 0.f, 0.f};
            if (anyb) {
                prev1 = true;
#pragma unroll
                for (int j = 0; j < 8; ++j) M1[j] = __ballot((m >> j) & 1);
#pragma unroll
                for (int j = 0; j < 8; ++j) {
                    unsigned long long bits = M1[j];
                    while (bits) {
                        int p = __builtin_ctzll(bits);
                        bits &= bits - 1;
                        int i = (p << 3) + j;
                        float4 qv = *(const float4*)(w2t + (size_t)i * H2 + 4 * lane);
                        I2[0]+=qv.x; I2[1]+=qv.y; I2[2]+=qv.z; I2[3]+=qv.w;
                    }
                }
            } else {
                prev1 = false;
            }

            // ---- layer-2 update ----
            unsigned m2 = 0;
#pragma unroll
            for (int j = 0; j < 4; ++j) {
                float v2n = fmaf(al2[j], v2[j], oml2[j] * (I2[j] - a2[j]));
                bool  sp  = v2n > 1.f;
                v2[j] = sp ? v2n - 1.f : v2n;
                a2[j] = fmaf(rh2[j], a2[j], ba2[j] * s2f[j]);
                s2f[j] = sp ? 1.f : 0.f;
                m2 |= (sp ? 1u : 0u) << j;
            }

            unsigned long long any2 = __ballot(m2 != 0);
            float io0 = 0.f, io1 = 0.f;
            if (any2) {                       // very rare (layer-2 never spikes here)
#pragma unroll
                for (int j = 0; j < 4; ++j) {
                    unsigned long long bits = __ballot((m2 >> j) & 1);
                    while (bits) {
                        int p = __builtin_ctzll(bits);
                        bits &= bits - 1;
                        int i = (p << 2) + j;
                        io0 += w3t[(size_t)i * NOUT + lane];
                        if (lane < NOUT - 64) io1 += w3t[(size_t)i * NOUT + 64 + lane];
                    }
                }
            }
            vo0 = fmaf(bo0, vo0, ombo0 * io0);
            vo1 = fmaf(bo1, vo1, ombo1 * io1);
            vs0 += vo0;
            vs1 += vo1;

#pragma unroll
            for (int j = 0; j < 8; ++j) cur[j] = nxt[j];
        }

        // stage next chunk AFTER gathers (keeps the vmem FIFO clean of staging)
        if (c + 1 < NC) stage(c + 1, buf ^ 1);
    }

    out[b * NOUT + lane] = vs0 * (1.f / (float)T_);
    if (lane < NOUT - 64) out[b * NOUT + 64 + lane] = vs1 * (1.f / (float)T_);
}

// ---------------- launch ----------------
extern "C" void kernel_launch(void* const* d_in, const int* in_sizes, int n_in,
                              void* d_out, int out_size, void* d_ws, size_t ws_size,
                              hipStream_t stream) {
    const float* x      = (const float*)d_in[0];   // [B][T][NIN]
    const float* w1     = (const float*)d_in[1];   // [H1][NIN]
    const float* w_rec  = (const float*)d_in[2];   // [H1][H1]
    const float* w2     = (const float*)d_in[3];   // [H2][H1]
    const float* w3     = (const float*)d_in[4];   // [NOUT][H2]
    const float* alpha1 = (const float*)d_in[5];
    const float* rho1   = (const float*)d_in[6];
    const float* beta_a1= (const float*)d_in[7];
    const float* alpha2 = (const float*)d_in[8];
    const float* rho2   = (const float*)d_in[9];
    const float* beta_a2= (const float*)d_in[10];
    const float* beta_out=(const float*)d_in[11];
    float* out = (float*)d_out;

    const int M = B_ * T_;                         // 19200

    size_t off = 0;
    auto take = [&](size_t bytes) {
        void* p = (char*)d_ws + off;
        off += (bytes + 255) & ~(size_t)255;
        return p;
    };
    float* I1ff = (float*)take((size_t)M * H1 * 4);            // 39.3 MB
    float* wrt  = (float*)take((size_t)H1 * H1 * 4);
    float* w2t  = (float*)take((size_t)H1 * H2 * 4);
    float* w3t  = (float*)take((size_t)H2 * NOUT * 4);
    unsigned short* xb  = (unsigned short*)take((size_t)M * KP * 2);   // 90.9 MB
    unsigned short* w1b = (unsigned short*)take((size_t)H1 * KP * 2);  // 2.4 MB

    transpose_k<<<(H1 * H1 + 255) / 256, 256, 0, stream>>>(w_rec, wrt, H1, H1);
    transpose_k<<<(H2 * H1 + 255) / 256, 256, 0, stream>>>(w2, w2t, H2, H1);
    transpose_k<<<(NOUT * H2 + 255) / 256, 256, 0, stream>>>(w3, w3t, NOUT, H2);

    // X and W -> bf16 (vectorized, HBM/L3-bound)
    int nx = M * (KP / 8);
    cvt_pad_bf16<<<(nx + 255) / 256, 256, 0, stream>>>(x, xb, M, NIN, KP);
    int nw = H1 * (KP / 8);
    cvt_pad_bf16<<<(nw + 255) / 256, 256, 0, stream>>>(w1, w1b, H1, NIN, KP);

    // 128x256-tile bf16 GEMM: 300 blocks x 512 threads
    gemm_bf16<<<300, 512, 0, stream>>>(xb, w1b, I1ff);

    snn_scan_wave<<<B_, 64, 0, stream>>>(I1ff, wrt, w2t, w3t,
                                         alpha1, rho1, beta_a1,
                                         alpha2, rho2, beta_a2,
                                         beta_out, out);
}